// Round 11
// baseline (458.033 us; speedup 1.0000x reference)
//
#include <hip/hip_runtime.h>
#include <stdint.h>

#define BB 8
#define SD 512

typedef unsigned short u16;
typedef __attribute__((ext_vector_type(8))) __bf16 bf16x8;
typedef __attribute__((ext_vector_type(16))) float f32x16;

// Static device scratch
__device__ float g_s[BB * 128];
__device__ u16 g_wtb[BB * 9 * 2 * 8192];   // [b][tap][h]: 16KB blocks, [slot][co] 16-B entries

typedef const __attribute__((address_space(1))) uint32_t* gp1;
typedef __attribute__((address_space(3))) uint32_t* lp3;

__device__ __forceinline__ void glds16(const void* g, void* l) {
    __builtin_amdgcn_global_load_lds((gp1)g, (lp3)l, 16, 0, 0);
}

__device__ __forceinline__ u16 f2bf(float f) {
    uint32_t u = __float_as_uint(f);
    u += 0x7FFFu + ((u >> 16) & 1u);   // RNE
    return (u16)(u >> 16);
}

__global__ void affine_kernel(const float* __restrict__ style,
                              const float* __restrict__ aff_w,
                              const float* __restrict__ aff_b) {
    int b = blockIdx.x;
    int ci = threadIdx.x;
    const float gain = 0.044194173824159216f;  // 1/sqrt(512)
    const float* st = style + b * SD;
    const float* aw = aff_w + ci * SD;
    float acc = 0.f;
    #pragma unroll 8
    for (int j = 0; j < SD; ++j) acc += st[j] * aw[j];
    g_s[b * 128 + ci] = acc * gain + aff_b[ci];
}

__global__ __launch_bounds__(256) void modulate_kernel(const float* __restrict__ w_base) {
    int blk = blockIdx.x;           // 0..B*CO-1
    int b = blk >> 7, co = blk & 127;
    int tid = threadIdx.x;
    const float wgain = 0.029462782549439483f;  // 1/sqrt(128*9)
    const int n = 1152;
    const float* wb = w_base + co * n;
    const float* sp = g_s + b * 128;

    float v[5];
    float sq = 0.f;
    #pragma unroll
    for (int i = 0; i < 5; ++i) {
        int idx = tid + i * 256;
        float w = 0.f;
        if (idx < n) {
            int ci = idx / 9;
            w = wb[idx] * wgain * sp[ci];
        }
        v[i] = w;
        sq += w * w;
    }
    #pragma unroll
    for (int off = 32; off > 0; off >>= 1) sq += __shfl_down(sq, off, 64);
    __shared__ float red[4];
    int lane = tid & 63, wvi = tid >> 6;
    if (lane == 0) red[wvi] = sq;
    __syncthreads();
    float tot = red[0] + red[1] + red[2] + red[3];
    float d = rsqrtf(tot + 1e-8f);
    #pragma unroll
    for (int i = 0; i < 5; ++i) {
        int idx = tid + i * 256;
        if (idx < n) {
            int ci = idx / 9;
            int k9 = idx - ci * 9;              // tap
            u16 hv = f2bf(v[i] * d);
            int slot = (ci & 63) >> 3, e = ci & 7;
            size_t base = ((size_t)(b * 9 + k9) * 2 + (ci >> 6)) * 8192;
            g_wtb[base + slot * 1024 + co * 8 + e] = hv;
        }
    }
}

// ---- fused conv helpers: X staging (reg path) ----
// main: wave wv owns octet-groups g = wv, wv+8, wv+16 (g = row*4 + slot).
// Each group: 8 runs (row, ci = s*8+j), lane = pixel x0-1+lane (64 px, clamped).
// tail: waves 0..5, row = wv, 8 entries (slot, tp) x 8 ci-members, px x0+63+tp.
__device__ __forceinline__ void stage_load(const float* __restrict__ xq, int x0, int y0,
                                           int wv, int lane, float xv[3][8], float* xtail) {
    #pragma unroll
    for (int gi = 0; gi < 3; ++gi) {
        int g = wv + gi * 8;
        int row = g >> 2, s = g & 3;
        int gy = y0 - 1 + row;
        int gyc = gy < 0 ? 0 : (gy > 255 ? 255 : gy);
        int gx = x0 - 1 + lane;
        int gxc = gx < 0 ? 0 : gx;
        bool ok = ((unsigned)gy < 256u) && (gx >= 0);
        #pragma unroll
        for (int j = 0; j < 8; ++j) {
            int ci = s * 8 + j;
            float v = xq[(size_t)ci * 65536 + gyc * 256 + gxc];
            xv[gi][j] = ok ? v : 0.f;
        }
    }
    if (wv < 6) {                        // wave-uniform
        int row = wv;
        int e = lane >> 3;               // 0..7: (slot, tp)
        int s = e >> 1, tp = e & 1;
        int ci = s * 8 + (lane & 7);
        int gy = y0 - 1 + row;
        int gyc = gy < 0 ? 0 : (gy > 255 ? 255 : gy);
        int gx = x0 + 63 + tp;
        int gxc = gx > 255 ? 255 : gx;
        bool ok = ((unsigned)gy < 256u) && (gx < 256);
        float v = xq[(size_t)ci * 65536 + gyc * 256 + gxc];
        *xtail = ok ? v : 0.f;
    }
}

__device__ __forceinline__ void stage_write(char* xsB, int wv, int lane,
                                            const float xv[3][8], float xtail) {
    #pragma unroll
    for (int gi = 0; gi < 3; ++gi) {
        int g = wv + gi * 8;
        int row = g >> 2, s = g & 3;
        uint32_t dw[4];
        #pragma unroll
        for (int d = 0; d < 4; ++d)
            dw[d] = (uint32_t)f2bf(xv[gi][2 * d]) |
                    ((uint32_t)f2bf(xv[gi][2 * d + 1]) << 16);
        int entry = (s * 6 + row) * 66 + lane;
        *(uint4*)(xsB + (size_t)entry * 16) = *(uint4*)dw;
    }
    if (wv < 6) {
        int row = wv;
        int e = lane >> 3;
        int s = e >> 1, tp = e & 1;
        int entry = (s * 6 + row) * 66 + 64 + tp;
        *(u16*)(xsB + (size_t)entry * 16 + (lane & 7) * 2) = f2bf(xtail);
    }
}

// Fused implicit-GEMM conv: per block: batch b, 64x4 px tile, all 128 co. 512 threads.
// X staged straight from fp32 x (coalesced 64-px runs, reg->LDS, plane-major).
// Quarter-ci phases (K=32/step), A ring-3 with counted vmcnt, raw barriers.
__global__ __launch_bounds__(512, 4) void conv_kernel(const float* __restrict__ x,
                                                      float* __restrict__ y) {
    __shared__ __align__(16) u16 xs[4 * 6 * 66 * 8];   // [slot][row][col] 16-B entries, 25344 B
    __shared__ __align__(16) u16 abr[3][4096];         // A ring, 3 x 8 KB

    const int b = blockIdx.y;
    const int t = blockIdx.x;                 // 0..255 (4 tx x 64 ty)
    const int swzt = (t & 7) * 32 + (t >> 3); // XCD swizzle (256 % 8 == 0)
    const int tx = swzt & 3, ty = swzt >> 2;
    const int x0 = tx * 64, y0 = ty * 4;
    const int tid = threadIdx.x;
    const int lane = tid & 63, wv = tid >> 6;
    const int l31 = lane & 31;
    const int l5 = lane >> 5;
    const int coHalf = (wv & 1) * 64;
    const int rw = wv >> 1;                   // wave's output row 0..3

    const char* wtbB = (const char*)(g_wtb) + (size_t)b * 294912;
    char* xsB = (char*)xs;
    const float* xb0 = x + (size_t)b * 128 * 65536;

    f32x16 acc[2][2];
    #pragma unroll
    for (int mf = 0; mf < 2; ++mf)
        #pragma unroll
        for (int nf = 0; nf < 2; ++nf)
            acc[mf][nf] = (f32x16){0.f};

    float xv[3][8];
    float xtail = 0.f;

    // ---- prologue: X quarter 0 + A0/A1 stages ----
    stage_load(xb0, x0, y0, wv, lane, xv, &xtail);
    glds16(wtbB + 0 + tid * 16, (char*)abr[0] + tid * 16);
    glds16(wtbB + 32768 + tid * 16, (char*)abr[1] + tid * 16);   // (tap1,h0) slots0..3
    stage_write(xsB, wv, lane, xv, xtail);
    asm volatile("s_waitcnt vmcnt(1) lgkmcnt(0)" ::: "memory");
    __builtin_amdgcn_sched_barrier(0);
    __builtin_amdgcn_s_barrier();

    #pragma unroll
    for (int u = 0; u < 36; ++u) {
        const int q = u / 9, tap = u - q * 9;

        // A stage for step u+2 into ring slot (u+2)%3
        if (u + 2 <= 35) {
            const int w = u + 2, qw = w / 9, tw = w - qw * 9;
            const char* src = wtbB + (tw * 2 + (qw >> 1)) * 16384 + (qw & 1) * 8192;
            glds16(src + tid * 16, (char*)abr[(u + 2) % 3] + tid * 16);
        }
        // X loads for next quarter (issued at each quarter's first tap)
        if (tap == 0 && q < 3)
            stage_load(xb0 + (size_t)(q + 1) * 32 * 65536, x0, y0, wv, lane, xv, &xtail);

        // compute from abr[u%3] + xs
        const int ky = tap / 3, kx = tap - ky * 3;
        const char* abuf = (const char*)abr[u % 3];
        #pragma unroll
        for (int ks = 0; ks < 2; ++ks) {
            const int slot = ks * 2 + l5;
            bf16x8 af[2];
            #pragma unroll
            for (int mf = 0; mf < 2; ++mf)
                af[mf] = *(const bf16x8*)(abuf + (size_t)(slot * 128 + coHalf + mf * 32 + l31) * 16);
            bf16x8 bfv[2];
            #pragma unroll
            for (int nf = 0; nf < 2; ++nf)
                bfv[nf] = *(const bf16x8*)(xsB +
                    (size_t)((slot * 6 + rw + ky) * 66 + nf * 32 + l31 + kx) * 16);
            __builtin_amdgcn_s_setprio(1);
            #pragma unroll
            for (int mf = 0; mf < 2; ++mf)
                #pragma unroll
                for (int nf = 0; nf < 2; ++nf)
                    acc[mf][nf] = __builtin_amdgcn_mfma_f32_32x32x16_bf16(
                        af[mf], bfv[nf], acc[mf][nf], 0, 0, 0);
            __builtin_amdgcn_s_setprio(0);
        }

        // counted-vmcnt sync: need A_{u+1} landed; X batch (24/25) + A_{u+2} may stay in flight
        if (u < 27 && tap < 2) {
            asm volatile("s_waitcnt vmcnt(25)" ::: "memory");
        } else if (u < 34) {
            asm volatile("s_waitcnt vmcnt(1)" ::: "memory");
        } else {
            asm volatile("s_waitcnt vmcnt(0)" ::: "memory");
        }
        __builtin_amdgcn_sched_barrier(0);
        __builtin_amdgcn_s_barrier();

        // quarter boundary: commit next quarter's X into xs
        if (tap == 8 && q < 3) {
            stage_write(xsB, wv, lane, xv, xtail);
            asm volatile("s_waitcnt lgkmcnt(0)" ::: "memory");
            __builtin_amdgcn_sched_barrier(0);
            __builtin_amdgcn_s_barrier();
        }
    }

    // ---- epilogue: C layout (32x32): col = lane&31, row = (j&3)+8*(j>>2)+4*(lane>>5) ----
    float* yb = y + (size_t)b * 128 * 65536;
    #pragma unroll
    for (int mf = 0; mf < 2; ++mf) {
        #pragma unroll
        for (int nf = 0; nf < 2; ++nf) {
            int gy = y0 + rw;
            int gx = x0 + nf * 32 + l31;
            #pragma unroll
            for (int j = 0; j < 16; ++j) {
                int co = coHalf + mf * 32 + (j & 3) + 8 * (j >> 2) + 4 * l5;
                yb[(size_t)co * 65536 + gy * 256 + gx] = acc[mf][nf][j];
            }
        }
    }
}

extern "C" void kernel_launch(void* const* d_in, const int* in_sizes, int n_in,
                              void* d_out, int out_size, void* d_ws, size_t ws_size,
                              hipStream_t stream) {
    const float* x = (const float*)d_in[0];
    const float* style = (const float*)d_in[1];
    const float* w_base = (const float*)d_in[2];
    const float* aff_w = (const float*)d_in[3];
    const float* aff_b = (const float*)d_in[4];
    float* y = (float*)d_out;

    affine_kernel<<<BB, 128, 0, stream>>>(style, aff_w, aff_b);
    modulate_kernel<<<BB * 128, 256, 0, stream>>>(w_base);
    conv_kernel<<<dim3(256, BB), 512, 0, stream>>>(x, y);
}

// Round 13
// 420.774 us; speedup vs baseline: 1.0886x; 1.0886x over previous
//
#include <hip/hip_runtime.h>
#include <stdint.h>

#define BB 8
#define SD 512

typedef unsigned short u16;
typedef __attribute__((ext_vector_type(8))) __bf16 bf16x8;
typedef __attribute__((ext_vector_type(16))) float f32x16;

// Static device scratch
__device__ float g_s[BB * 128];
__device__ u16 g_wtb[BB * 9 * 2 * 8192];                  // [b][tap][h]: 16KB blocks, [slot][co] 16-B entries
__device__ u16 g_xb[(size_t)BB * 258 * 258 * 128 + 2048]; // [b][gy_p][gx_p][slot] pixel-major

typedef const __attribute__((address_space(1))) uint32_t* gp1;
typedef __attribute__((address_space(3))) uint32_t* lp3;

__device__ __forceinline__ void glds16(const void* g, void* l) {
    __builtin_amdgcn_global_load_lds((gp1)g, (lp3)l, 16, 0, 0);
}

__device__ __forceinline__ u16 f2bf(float f) {
    uint32_t u = __float_as_uint(f);
    u += 0x7FFFu + ((u >> 16) & 1u);   // RNE
    return (u16)(u >> 16);
}

__global__ void affine_kernel(const float* __restrict__ style,
                              const float* __restrict__ aff_w,
                              const float* __restrict__ aff_b) {
    int b = blockIdx.x;
    int ci = threadIdx.x;
    const float gain = 0.044194173824159216f;  // 1/sqrt(512)
    const float* st = style + b * SD;
    const float* aw = aff_w + ci * SD;
    float acc = 0.f;
    #pragma unroll 8
    for (int j = 0; j < SD; ++j) acc += st[j] * aw[j];
    g_s[b * 128 + ci] = acc * gain + aff_b[ci];
}

__global__ __launch_bounds__(256) void modulate_kernel(const float* __restrict__ w_base) {
    int blk = blockIdx.x;
    int b = blk >> 7, co = blk & 127;
    int tid = threadIdx.x;
    const float wgain = 0.029462782549439483f;  // 1/sqrt(128*9)
    const int n = 1152;
    const float* wb = w_base + co * n;
    const float* sp = g_s + b * 128;

    float v[5];
    float sq = 0.f;
    #pragma unroll
    for (int i = 0; i < 5; ++i) {
        int idx = tid + i * 256;
        float w = 0.f;
        if (idx < n) {
            int ci = idx / 9;
            w = wb[idx] * wgain * sp[ci];
        }
        v[i] = w;
        sq += w * w;
    }
    #pragma unroll
    for (int off = 32; off > 0; off >>= 1) sq += __shfl_down(sq, off, 64);
    __shared__ float red[4];
    int lane = tid & 63, wvi = tid >> 6;
    if (lane == 0) red[wvi] = sq;
    __syncthreads();
    float tot = red[0] + red[1] + red[2] + red[3];
    float d = rsqrtf(tot + 1e-8f);
    #pragma unroll
    for (int i = 0; i < 5; ++i) {
        int idx = tid + i * 256;
        if (idx < n) {
            int ci = idx / 9;
            int k9 = idx - ci * 9;
            u16 hv = f2bf(v[i] * d);
            int slot = (ci & 63) >> 3, e = ci & 7;
            size_t base = ((size_t)(b * 9 + k9) * 2 + (ci >> 6)) * 8192;
            g_wtb[base + slot * 1024 + co * 8 + e] = hv;
        }
    }
}

// zero halo borders of g_xb (pixel-major)
__global__ __launch_bounds__(256) void zero_border_kernel() {
    int b = blockIdx.x;
    uint4 z = make_uint4(0, 0, 0, 0);
    char* xbB = (char*)g_xb;
    for (int i = threadIdx.x; i < 16448; i += 256) {
        size_t pix; int k;
        if (i < 4128)       { pix = (size_t)(b * 258 + 0)   * 258 + (i >> 4);            k = i & 15; }
        else if (i < 8256)  { int j = i - 4128;  pix = (size_t)(b * 258 + 257) * 258 + (j >> 4);       k = j & 15; }
        else if (i < 12352) { int j = i - 8256;  pix = (size_t)(b * 258 + 1 + (j >> 4)) * 258 + 0;     k = j & 15; }
        else                { int j = i - 12352; pix = (size_t)(b * 258 + 1 + (j >> 4)) * 258 + 257;   k = j & 15; }
        *(uint4*)(xbB + pix * 256 + (size_t)k * 16) = z;
    }
}

// transpose+convert: x [b][ci][h][w] fp32 -> g_xb [b][gy_p][gx_p][slot] bf16
__global__ __launch_bounds__(256) void transpose_kernel(const float* __restrict__ x) {
    __shared__ __align__(16) u16 t_lds[64 * 128];
    const int chunk = blockIdx.x;
    const int gy = blockIdx.y;
    const int b = blockIdx.z;
    const int px0 = chunk * 64;
    const int tid = threadIdx.x;
    const int pq = tid & 15;
    const int cig = tid >> 4;

    const float* base = x + (size_t)b * 128 * 65536 + (size_t)gy * 256 + px0 + pq * 4;
    char* ldsB = (char*)t_lds;

    float4 v[8];
    #pragma unroll
    for (int c = 0; c < 8; ++c)
        v[c] = *(const float4*)(base + (size_t)(cig * 8 + c) * 65536);

    #pragma unroll
    for (int j = 0; j < 4; ++j) {
        uint32_t dw[4];
        #pragma unroll
        for (int d = 0; d < 4; ++d) {
            const float* lo4 = (const float*)&v[2 * d];
            const float* hi4 = (const float*)&v[2 * d + 1];
            dw[d] = (uint32_t)f2bf(lo4[j]) | ((uint32_t)f2bf(hi4[j]) << 16);
        }
        int px = pq * 4 + j;
        int key = (px0 + px + 1) & 7;
        int slot = cig ^ key;
        *(uint4*)(ldsB + px * 256 + slot * 16) = *(uint4*)dw;
    }
    __syncthreads();

    char* outB = (char*)g_xb;
    #pragma unroll
    for (int it = 0; it < 4; ++it) {
        int flat = it * 256 + tid;
        int r = flat >> 4, k = flat & 15;
        int key = (px0 + r + 1) & 7;
        uint4 val = *(const uint4*)(ldsB + r * 256 + ((k ^ key) << 4));
        size_t pix = ((size_t)(b * 258 + gy + 1)) * 258 + (px0 + r + 1);
        *(uint4*)(outB + pix * 256 + k * 16) = val;
    }
}

// Implicit-GEMM conv, counted-vmcnt A ring-4 (8-KB halves), 36 half-steps.
__global__ __launch_bounds__(512, 4) void conv_kernel(float* __restrict__ y) {
    __shared__ __align__(16) u16 xs[2720 * 8];        // plane-major, 43520 B
    __shared__ __align__(16) u16 abr[4][4096];        // A ring-4, 4 x 8 KB

    const int b = blockIdx.y;
    const int t = blockIdx.x;
    const int swzt = (t & 7) * 32 + (t >> 3);
    const int tx = swzt & 7, ty = swzt >> 3;
    const int y0 = ty * 8, x0 = tx * 32;
    const int tid = threadIdx.x;
    const int lane = tid & 63, wv = tid >> 6;
    const int l31 = lane & 31;
    const int l5 = lane >> 5;
    const int coHalf = (wv & 1) * 64;
    const int py0w = (wv >> 1) * 2;

    const char* xbB = (const char*)g_xb;
    const char* wtbB = (const char*)(g_wtb) + (size_t)b * 294912;
    char* xsB = (char*)xs;

    f32x16 acc[2][2];
    #pragma unroll
    for (int mf = 0; mf < 2; ++mf)
        #pragma unroll
        for (int rf = 0; rf < 2; ++rf)
            acc[mf][rf] = (f32x16){0.f};

    // ---- prologue: va loads -> ds_write -> vb loads -> A0..A3 issues ----
    uint4 va[6], vb[6];
    #pragma unroll
    for (int it = 0; it < 6; ++it) {
        int f = it * 512 + tid;
        if (f < 2720) {
            int p = f >> 3, s2 = f & 7;
            int row = p / 34, col = p - row * 34;
            size_t pix = (size_t)(b * 258 + y0 + row) * 258 + (x0 + col);
            va[it] = *(const uint4*)(xbB + pix * 256 + s2 * 16);
        }
    }
    #pragma unroll
    for (int it = 0; it < 6; ++it) {
        int f = it * 512 + tid;
        if (f < 2720) {
            int p = f >> 3, s2 = f & 7;
            *(uint4*)(xsB + (size_t)(s2 * 340 + p) * 16) = va[it];
        }
    }
    #pragma unroll
    for (int it = 0; it < 6; ++it) {
        int f = it * 512 + tid;
        if (f < 2720) {
            int p = f >> 3, s2 = f & 7;
            int row = p / 34, col = p - row * 34;
            size_t pix = (size_t)(b * 258 + y0 + row) * 258 + (x0 + col);
            vb[it] = *(const uint4*)(xbB + pix * 256 + 128 + s2 * 16);
        }
    }
    __builtin_amdgcn_sched_barrier(0);
    // A halves 0..3: half a -> tap = a>>1, h = 0, halfsel = a&1
    //   byte offset = ((tap*2 + 0)*2 + halfsel)*8192 = (tap*4 + halfsel)*8192
    #pragma unroll
    for (int a = 0; a < 4; ++a) {
        const char* src = wtbB + (size_t)(((a >> 1) * 4 + (a & 1)) * 8192);
        glds16(src + tid * 16, (char*)abr[a] + tid * 16);
    }
    __builtin_amdgcn_sched_barrier(0);
    asm volatile("s_waitcnt vmcnt(3) lgkmcnt(0)" ::: "memory");
    __builtin_amdgcn_sched_barrier(0);
    __builtin_amdgcn_s_barrier();

    // ---- main loop: 36 half-steps, 2 raw barriers each, loads never drain ----
    #pragma unroll
    for (int s = 0; s < 36; ++s) {
        if (s == 18) {
            #pragma unroll
            for (int it = 0; it < 6; ++it) {
                int f = it * 512 + tid;
                if (f < 2720) {
                    int p = f >> 3, s2 = f & 7;
                    *(uint4*)(xsB + (size_t)(s2 * 340 + p) * 16) = vb[it];
                }
            }
            asm volatile("s_waitcnt lgkmcnt(0)" ::: "memory");
            __builtin_amdgcn_sched_barrier(0);
            __builtin_amdgcn_s_barrier();
        }

        const int u = s >> 1;
        const int tap = (u >= 9) ? (u - 9) : u;
        const int ky = tap / 3, kx = tap - ky * 3;
        const int halfsel = s & 1;
        const char* abuf = (const char*)abr[s & 3];
        const int prow = (py0w + ky) * 34 + l31 + kx;

        #pragma unroll
        for (int ks = 0; ks < 2; ++ks) {
            const int cl = ks * 2 + l5;            // local slot in A half
            const int cig = halfsel * 4 + cl;      // global ci-plane in xs
            bf16x8 af[2];
            #pragma unroll
            for (int mf = 0; mf < 2; ++mf)
                af[mf] = *(const bf16x8*)(abuf + (size_t)(cl * 128 + coHalf + mf * 32 + l31) * 16);
            bf16x8 bfv[2];
            #pragma unroll
            for (int rf = 0; rf < 2; ++rf)
                bfv[rf] = *(const bf16x8*)(xsB + (size_t)(cig * 340 + prow + rf * 34) * 16);
            __builtin_amdgcn_s_setprio(1);
            #pragma unroll
            for (int mf = 0; mf < 2; ++mf)
                #pragma unroll
                for (int rf = 0; rf < 2; ++rf)
                    acc[mf][rf] = __builtin_amdgcn_mfma_f32_32x32x16_bf16(
                        af[mf], bfv[rf], acc[mf][rf], 0, 0, 0);
            __builtin_amdgcn_s_setprio(0);
        }

        asm volatile("s_waitcnt lgkmcnt(0)" ::: "memory");
        __builtin_amdgcn_sched_barrier(0);
        __builtin_amdgcn_s_barrier();          // all reads of ring slot s&3 done

        if (s + 4 <= 35) {
            const int w = s + 4, uw = w >> 1;
            const int tw = (uw >= 9) ? (uw - 9) : uw;
            const int hw = (uw >= 9) ? 1 : 0;
            const char* src = wtbB + ((tw * 2 + hw) * 2 + (w & 1)) * 8192;
            glds16(src + tid * 16, (char*)abr[s & 3] + tid * 16);
        }
        __builtin_amdgcn_sched_barrier(0);
        if (s <= 31)      asm volatile("s_waitcnt vmcnt(3)" ::: "memory");
        else if (s == 32) asm volatile("s_waitcnt vmcnt(2)" ::: "memory");
        else if (s == 33) asm volatile("s_waitcnt vmcnt(1)" ::: "memory");
        else if (s == 34) asm volatile("s_waitcnt vmcnt(0)" ::: "memory");
        __builtin_amdgcn_sched_barrier(0);
        __builtin_amdgcn_s_barrier();          // A_{s+1} visible to all
    }

    // ---- epilogue ----
    float* yb = y + (size_t)b * 128 * 65536;
    #pragma unroll
    for (int mf = 0; mf < 2; ++mf) {
        #pragma unroll
        for (int rf = 0; rf < 2; ++rf) {
            int gy = y0 + py0w + rf;
            int gx = x0 + l31;
            #pragma unroll
            for (int j = 0; j < 16; ++j) {
                int co = coHalf + mf * 32 + (j & 3) + 8 * (j >> 2) + 4 * l5;
                yb[(size_t)co * 65536 + gy * 256 + gx] = acc[mf][rf][j];
            }
        }
    }
}

extern "C" void kernel_launch(void* const* d_in, const int* in_sizes, int n_in,
                              void* d_out, int out_size, void* d_ws, size_t ws_size,
                              hipStream_t stream) {
    const float* x = (const float*)d_in[0];
    const float* style = (const float*)d_in[1];
    const float* w_base = (const float*)d_in[2];
    const float* aff_w = (const float*)d_in[3];
    const float* aff_b = (const float*)d_in[4];
    float* y = (float*)d_out;

    affine_kernel<<<BB, 128, 0, stream>>>(style, aff_w, aff_b);
    modulate_kernel<<<BB * 128, 256, 0, stream>>>(w_base);
    zero_border_kernel<<<BB, 256, 0, stream>>>();
    transpose_kernel<<<dim3(4, 256, BB), 256, 0, stream>>>(x);
    conv_kernel<<<dim3(256, BB), 512, 0, stream>>>(y);
}

// Round 14
// 342.985 us; speedup vs baseline: 1.3354x; 1.2268x over previous
//
#include <hip/hip_runtime.h>
#include <stdint.h>

#define BB 8
#define SD 512

typedef unsigned short u16;
typedef __attribute__((ext_vector_type(8))) __bf16 bf16x8;
typedef __attribute__((ext_vector_type(16))) float f32x16;

// Static device scratch
__device__ float g_s[BB * 128];
__device__ u16 g_wtb[BB * 9 * 2 * 8192];                  // [b][tap][chunk]: 16KB blocks, [slot][co] 16-B entries
__device__ u16 g_xb[(size_t)BB * 258 * 258 * 128 + 2048]; // [b][gy_p][gx_p][ci] pixel-major, in-row XOR swizzled

typedef const __attribute__((address_space(1))) uint32_t* gp1;
typedef __attribute__((address_space(3))) uint32_t* lp3;

__device__ __forceinline__ void glds16(const void* g, void* l) {
    __builtin_amdgcn_global_load_lds((gp1)g, (lp3)l, 16, 0, 0);
}
__device__ __forceinline__ void glds4(const void* g, void* l) {
    __builtin_amdgcn_global_load_lds((gp1)g, (lp3)l, 4, 0, 0);
}

__device__ __forceinline__ u16 f2bf(float f) {
    uint32_t u = __float_as_uint(f);
    u += 0x7FFFu + ((u >> 16) & 1u);   // RNE
    return (u16)(u >> 16);
}

__global__ void affine_kernel(const float* __restrict__ style,
                              const float* __restrict__ aff_w,
                              const float* __restrict__ aff_b) {
    int b = blockIdx.x;
    int ci = threadIdx.x;
    const float gain = 0.044194173824159216f;  // 1/sqrt(512)
    const float* st = style + b * SD;
    const float* aw = aff_w + ci * SD;
    float acc = 0.f;
    #pragma unroll 8
    for (int j = 0; j < SD; ++j) acc += st[j] * aw[j];
    g_s[b * 128 + ci] = acc * gain + aff_b[ci];
}

__global__ __launch_bounds__(256) void modulate_kernel(const float* __restrict__ w_base) {
    int blk = blockIdx.x;           // 0..B*CO-1
    int b = blk >> 7, co = blk & 127;
    int tid = threadIdx.x;
    const float wgain = 0.029462782549439483f;  // 1/sqrt(128*9)
    const int n = 1152;
    const float* wb = w_base + co * n;
    const float* sp = g_s + b * 128;

    float v[5];
    float sq = 0.f;
    #pragma unroll
    for (int i = 0; i < 5; ++i) {
        int idx = tid + i * 256;
        float w = 0.f;
        if (idx < n) {
            int ci = idx / 9;
            w = wb[idx] * wgain * sp[ci];
        }
        v[i] = w;
        sq += w * w;
    }
    #pragma unroll
    for (int off = 32; off > 0; off >>= 1) sq += __shfl_down(sq, off, 64);
    __shared__ float red[4];
    int lane = tid & 63, wvi = tid >> 6;
    if (lane == 0) red[wvi] = sq;
    __syncthreads();
    float tot = red[0] + red[1] + red[2] + red[3];
    float d = rsqrtf(tot + 1e-8f);
    #pragma unroll
    for (int i = 0; i < 5; ++i) {
        int idx = tid + i * 256;
        if (idx < n) {
            int ci = idx / 9;
            int k9 = idx - ci * 9;              // tap
            u16 hv = f2bf(v[i] * d);
            // block [b][tap][chunk]; within: entry (slot, co), u16 pos e  -> conflict-free A reads
            int slot = (ci & 63) >> 3, e = ci & 7;
            size_t base = ((size_t)(b * 9 + k9) * 2 + (ci >> 6)) * 8192;
            g_wtb[base + slot * 1024 + co * 8 + e] = hv;
        }
    }
}

// zero halo borders of g_xb (pixel-major)
__global__ __launch_bounds__(256) void zero_border_kernel() {
    int b = blockIdx.x;
    uint4 z = make_uint4(0, 0, 0, 0);
    char* xbB = (char*)g_xb;
    for (int i = threadIdx.x; i < 16448; i += 256) {
        size_t pix; int k;
        if (i < 4128)       { pix = (size_t)(b * 258 + 0)   * 258 + (i >> 4);            k = i & 15; }
        else if (i < 8256)  { int j = i - 4128;  pix = (size_t)(b * 258 + 257) * 258 + (j >> 4);       k = j & 15; }
        else if (i < 12352) { int j = i - 8256;  pix = (size_t)(b * 258 + 1 + (j >> 4)) * 258 + 0;     k = j & 15; }
        else                { int j = i - 12352; pix = (size_t)(b * 258 + 1 + (j >> 4)) * 258 + 257;   k = j & 15; }
        *(uint4*)(xbB + pix * 256 + (size_t)k * 16) = z;
    }
}

// transpose+convert: x [b][ci][h][w] fp32 -> g_xb [b][gy_p][gx_p][ci] bf16, in-row XOR swizzle
__global__ __launch_bounds__(256) void transpose_kernel(const float* __restrict__ x) {
    __shared__ __align__(16) u16 t_lds[64 * 128];   // 16 KB
    const int chunk = blockIdx.x;        // 0..3 (64-px chunk)
    const int gy = blockIdx.y;           // 0..255
    const int b = blockIdx.z;
    const int px0 = chunk * 64;
    const int tid = threadIdx.x;
    const int pq = tid & 15;             // pixel quad: px = pq*4 + j
    const int cig = tid >> 4;            // 16-B ci group (8 ci), 0..15

    const float* base = x + (size_t)b * 128 * 65536 + (size_t)gy * 256 + px0 + pq * 4;
    char* ldsB = (char*)t_lds;

    float4 v[8];
    #pragma unroll
    for (int c = 0; c < 8; ++c)
        v[c] = *(const float4*)(base + (size_t)(cig * 8 + c) * 65536);

    #pragma unroll
    for (int j = 0; j < 4; ++j) {
        uint32_t dw[4];
        #pragma unroll
        for (int d = 0; d < 4; ++d) {
            const float* lo4 = (const float*)&v[2 * d];
            const float* hi4 = (const float*)&v[2 * d + 1];
            dw[d] = (uint32_t)f2bf(lo4[j]) | ((uint32_t)f2bf(hi4[j]) << 16);
        }
        int px = pq * 4 + j;                 // within chunk
        int key = (px0 + px + 1) & 7;        // (gx_p)&7
        int slot = cig ^ key;
        *(uint4*)(ldsB + px * 256 + slot * 16) = *(uint4*)dw;
    }
    __syncthreads();

    char* outB = (char*)g_xb;
    #pragma unroll
    for (int it = 0; it < 4; ++it) {
        int flat = it * 256 + tid;
        int r = flat >> 4, k = flat & 15;
        size_t pix = ((size_t)(b * 258 + gy + 1)) * 258 + (px0 + r + 1);
        *(uint4*)(outB + pix * 256 + k * 16) = *(const uint4*)(ldsB + r * 256 + k * 16);
    }
}

// Implicit-GEMM conv: per block: batch b, 32x8 px tile, all 128 co. 512 threads.
// 32x32x16 MFMA, X staged in ci-halves from g_xb -> 74.5 KB LDS -> 2 blocks/CU.
// A path: [slot][co] layout -> contiguous conflict-free fragment reads.
__global__ __launch_bounds__(512, 4) void conv_kernel(float* __restrict__ y) {
    __shared__ __align__(16) u16 xs[10 * 34 * 64];    // [row][col][ci-half] 43520 B
    __shared__ __align__(16) u16 ab[2][8192];         // A double buffer, 2x16 KB

    const int b = blockIdx.y;
    const int t = blockIdx.x;                 // 0..255
    const int swzt = (t & 7) * 32 + (t >> 3); // XCD-aware swizzle (256 % 8 == 0)
    const int tx = swzt & 7, ty = swzt >> 3;
    const int y0 = ty * 8, x0 = tx * 32;
    const int tid = threadIdx.x;
    const int lane = tid & 63, wv = tid >> 6;
    const int l31 = lane & 31;                // px-col / co-row within MFMA tile
    const int l5 = lane >> 5;                 // k-group select
    const int coHalf = (wv & 1) * 64;         // wave co origin
    const int py0w = (wv >> 1) * 2;           // wave row origin (2 rows/wave)

    const char* xbB = (const char*)g_xb;
    const char* wtbB = (const char*)(g_wtb) + (size_t)b * 294912;
    char* xsB = (char*)xs;

    f32x16 acc[2][2];
    #pragma unroll
    for (int mf = 0; mf < 2; ++mf)
        #pragma unroll
        for (int rf = 0; rf < 2; ++rf)
            acc[mf][rf] = (f32x16){0.f};

    for (int h = 0; h < 2; ++h) {
        // ---- stage X ci-half h from g_xb: 10 rows x (4 glds16 + 1 glds4) ----
        for (int i = wv; i < 50; i += 8) {
            int row = i / 5, sub = i - row * 5;
            size_t pixb = ((size_t)(b * 258 + y0 + row) * 258 + x0) * 256 + h * 128;
            char* dst = xsB + row * 4352;
            if (sub < 4) {
                // 8 px per inst: lane l -> px c = sub*8 + l/8, byte (l&7)*16 within 128B half
                glds16(xbB + pixb + (size_t)(sub * 8 + (lane >> 3)) * 256 + (lane & 7) * 16,
                       dst + sub * 1024);
            } else {
                // last 2 px: lane l -> px 32 + l/32, byte (l&31)*4
                glds4(xbB + pixb + (size_t)(32 + (lane >> 5)) * 256 + (lane & 31) * 4,
                      dst + 4096);
            }
        }
        if (h == 0) {
            // stage A step 0 (tap 0, chunk 0)
            #pragma unroll
            for (int q = 0; q < 2; ++q) {
                int j = wv * 2 + q;
                glds16(wtbB + j * 1024 + lane * 16, (char*)ab[0] + j * 1024);
            }
        }
        __syncthreads();

        for (int tap = 0; tap < 9; ++tap) {
            int s = h * 9 + tap;
            if (s < 17) {
                int ns = s + 1;
                int ntap = (ns >= 9) ? (ns - 9) : ns;
                int nh = (ns >= 9) ? 1 : h;
                const char* src = wtbB + (ntap * 2 + nh) * 16384;
                char* dst = (char*)ab[ns & 1];
                #pragma unroll
                for (int q = 0; q < 2; ++q) {
                    int j = wv * 2 + q;
                    glds16(src + j * 1024 + lane * 16, dst + j * 1024);
                }
            }

            const int ky = tap / 3, kx = tap - ky * 3;
            const char* abuf = (const char*)ab[s & 1];
            const int bcol = l31 + kx;                 // xs col 0..33
            const int bkey = bcol & 7;                 // x0 % 8 == 0
            const int brow_base = (py0w + ky) * 34 + bcol;

            #pragma unroll
            for (int ks = 0; ks < 4; ++ks) {           // K = 64 per half, steps of 16
                const int cig = ks * 2 + l5;           // 16B-slot 0..7
                bf16x8 af[2];
                #pragma unroll
                for (int mf = 0; mf < 2; ++mf) {
                    int co = coHalf + mf * 32 + l31;
                    af[mf] = *(const bf16x8*)(abuf + (size_t)(cig * 128 + co) * 16);
                }
                bf16x8 bf[2];
                #pragma unroll
                for (int rf = 0; rf < 2; ++rf)
                    bf[rf] = *(const bf16x8*)(xsB + (brow_base + rf * 34) * 128 +
                                              ((cig ^ bkey) << 4));
                __builtin_amdgcn_s_setprio(1);
                #pragma unroll
                for (int mf = 0; mf < 2; ++mf)
                    #pragma unroll
                    for (int rf = 0; rf < 2; ++rf)
                        acc[mf][rf] = __builtin_amdgcn_mfma_f32_32x32x16_bf16(
                            af[mf], bf[rf], acc[mf][rf], 0, 0, 0);
                __builtin_amdgcn_s_setprio(0);
            }
            __syncthreads();
        }
    }

    // ---- epilogue: C layout (32x32): col = lane&31, row = (j&3)+8*(j>>2)+4*(lane>>5) ----
    float* yb = y + (size_t)b * 128 * 65536;
    #pragma unroll
    for (int mf = 0; mf < 2; ++mf) {
        #pragma unroll
        for (int rf = 0; rf < 2; ++rf) {
            int gy = y0 + py0w + rf;
            int gx = x0 + l31;
            #pragma unroll
            for (int j = 0; j < 16; ++j) {
                int co = coHalf + mf * 32 + (j & 3) + 8 * (j >> 2) + 4 * l5;
                yb[(size_t)co * 65536 + gy * 256 + gx] = acc[mf][rf][j];
            }
        }
    }
}

extern "C" void kernel_launch(void* const* d_in, const int* in_sizes, int n_in,
                              void* d_out, int out_size, void* d_ws, size_t ws_size,
                              hipStream_t stream) {
    const float* x = (const float*)d_in[0];
    const float* style = (const float*)d_in[1];
    const float* w_base = (const float*)d_in[2];
    const float* aff_w = (const float*)d_in[3];
    const float* aff_b = (const float*)d_in[4];
    float* y = (float*)d_out;

    affine_kernel<<<BB, 128, 0, stream>>>(style, aff_w, aff_b);
    modulate_kernel<<<BB * 128, 256, 0, stream>>>(w_base);
    zero_border_kernel<<<BB, 256, 0, stream>>>();
    transpose_kernel<<<dim3(4, 256, BB), 256, 0, stream>>>(x);
    conv_kernel<<<dim3(256, BB), 512, 0, stream>>>(y);
}

// Round 15
// 326.679 us; speedup vs baseline: 1.4021x; 1.0499x over previous
//
#include <hip/hip_runtime.h>
#include <stdint.h>

#define BB 8
#define SD 512

typedef unsigned short u16;
typedef __attribute__((ext_vector_type(8))) __bf16 bf16x8;
typedef __attribute__((ext_vector_type(16))) float f32x16;

// Static device scratch
__device__ float g_s[BB * 128];
__device__ u16 g_wtb[BB * 9 * 2 * 8192];                  // [b][tap][chunk]: 16KB blocks, swizzled [co][ci64^((co&7)<<3)]
__device__ u16 g_xb[(size_t)BB * 258 * 258 * 128 + 2048]; // [b][gy_p][gx_p][ci] bf16, swizzled per pixel

typedef const __attribute__((address_space(1))) uint32_t* gp1;
typedef __attribute__((address_space(3))) uint32_t* lp3;

__device__ __forceinline__ void glds16(const void* g, void* l) {
    __builtin_amdgcn_global_load_lds((gp1)g, (lp3)l, 16, 0, 0);
}
__device__ __forceinline__ void glds4(const void* g, void* l) {
    __builtin_amdgcn_global_load_lds((gp1)g, (lp3)l, 4, 0, 0);
}

__device__ __forceinline__ u16 f2bf(float f) {
    uint32_t u = __float_as_uint(f);
    u += 0x7FFFu + ((u >> 16) & 1u);   // RNE
    return (u16)(u >> 16);
}

__global__ void affine_kernel(const float* __restrict__ style,
                              const float* __restrict__ aff_w,
                              const float* __restrict__ aff_b) {
    int b = blockIdx.x;
    int ci = threadIdx.x;
    const float gain = 0.044194173824159216f;  // 1/sqrt(512)
    const float* st = style + b * SD;
    const float* aw = aff_w + ci * SD;
    float acc = 0.f;
    #pragma unroll 8
    for (int j = 0; j < SD; ++j) acc += st[j] * aw[j];
    g_s[b * 128 + ci] = acc * gain + aff_b[ci];
}

__global__ __launch_bounds__(256) void modulate_kernel(const float* __restrict__ w_base) {
    int blk = blockIdx.x;           // 0..B*CO-1
    int b = blk >> 7, co = blk & 127;
    int tid = threadIdx.x;
    const float wgain = 0.029462782549439483f;  // 1/sqrt(128*9)
    const int n = 1152;
    const float* wb = w_base + co * n;
    const float* sp = g_s + b * 128;

    float v[5];
    float sq = 0.f;
    #pragma unroll
    for (int i = 0; i < 5; ++i) {
        int idx = tid + i * 256;
        float w = 0.f;
        if (idx < n) {
            int ci = idx / 9;
            w = wb[idx] * wgain * sp[ci];
        }
        v[i] = w;
        sq += w * w;
    }
    #pragma unroll
    for (int off = 32; off > 0; off >>= 1) sq += __shfl_down(sq, off, 64);
    __shared__ float red[4];
    int lane = tid & 63, wvi = tid >> 6;
    if (lane == 0) red[wvi] = sq;
    __syncthreads();
    float tot = red[0] + red[1] + red[2] + red[3];
    float d = rsqrtf(tot + 1e-8f);
    #pragma unroll
    for (int i = 0; i < 5; ++i) {
        int idx = tid + i * 256;
        if (idx < n) {
            int ci = idx / 9;
            int k9 = idx - ci * 9;              // tap
            u16 hv = f2bf(v[i] * d);
            int ci64 = ci & 63;
            // swizzled u16 index: co*64 + (ci64 ^ ((co&7)<<3))
            size_t base = ((size_t)(b * 9 + k9) * 2 + (ci >> 6)) * 8192;
            g_wtb[base + co * 64 + (ci64 ^ ((co & 7) << 3))] = hv;
        }
    }
}

// zero halo borders of g_xb
__global__ __launch_bounds__(256) void zero_border_kernel() {
    int b = blockIdx.x;
    uint4 z = make_uint4(0, 0, 0, 0);
    char* xbB = (char*)g_xb;
    for (int i = threadIdx.x; i < 16448; i += 256) {
        size_t pix; int k;
        if (i < 4128)       { pix = (size_t)(b * 258 + 0)   * 258 + (i >> 4);            k = i & 15; }
        else if (i < 8256)  { int j = i - 4128;  pix = (size_t)(b * 258 + 257) * 258 + (j >> 4);       k = j & 15; }
        else if (i < 12352) { int j = i - 8256;  pix = (size_t)(b * 258 + 1 + (j >> 4)) * 258 + 0;     k = j & 15; }
        else                { int j = i - 12352; pix = (size_t)(b * 258 + 1 + (j >> 4)) * 258 + 257;   k = j & 15; }
        *(uint4*)(xbB + pix * 256 + (size_t)k * 16) = z;
    }
}

// transpose+convert v2: x [b][ci][h][w] fp32 -> g_xb [b][h+1][w+1][ci] bf16 (swizzled)
__global__ __launch_bounds__(256) void transpose_kernel(const float* __restrict__ x) {
    __shared__ __align__(16) u16 t_lds[64 * 128];   // 16 KB
    const int chunk = blockIdx.x;        // 0..3 (64-px chunk)
    const int gy = blockIdx.y;           // 0..255
    const int b = blockIdx.z;
    const int px0 = chunk * 64;
    const int tid = threadIdx.x;
    const int pq = tid & 15;             // pixel quad: px = px0 + pq*4 + j
    const int cig = tid >> 4;            // 16-B ci group (8 ci), 0..15

    const float* base = x + (size_t)b * 128 * 65536 + (size_t)gy * 256 + px0 + pq * 4;
    char* ldsB = (char*)t_lds;

    float4 v[8];
    #pragma unroll
    for (int c = 0; c < 8; ++c)
        v[c] = *(const float4*)(base + (size_t)(cig * 8 + c) * 65536);

    #pragma unroll
    for (int j = 0; j < 4; ++j) {
        uint32_t dw[4];
        #pragma unroll
        for (int d = 0; d < 4; ++d) {
            const float* lo4 = (const float*)&v[2 * d];
            const float* hi4 = (const float*)&v[2 * d + 1];
            dw[d] = (uint32_t)f2bf(lo4[j]) | ((uint32_t)f2bf(hi4[j]) << 16);
        }
        int px = pq * 4 + j;                 // within chunk
        int key = (px0 + px + 1) & 7;        // (gx_p)&7
        int slot = cig ^ key;
        *(uint4*)(ldsB + px * 256 + slot * 16) = *(uint4*)dw;
    }
    __syncthreads();

    // write out 64 rows x 256B, fully coalesced
    char* outB = (char*)g_xb;
    #pragma unroll
    for (int it = 0; it < 4; ++it) {
        int flat = it * 256 + tid;
        int r = flat >> 4, k = flat & 15;
        size_t pix = ((size_t)(b * 258 + gy + 1)) * 258 + (px0 + r + 1);
        *(uint4*)(outB + pix * 256 + k * 16) = *(const uint4*)(ldsB + r * 256 + k * 16);
    }
}

// Implicit-GEMM conv: per block: batch b, 32x8 px tile, all 128 co. 512 threads.
// 32x32x16 MFMA, X staged in ci-halves from g_xb -> 74.5 KB LDS -> 2 blocks/CU.
__global__ __launch_bounds__(512, 4) void conv_kernel(float* __restrict__ y) {
    __shared__ __align__(16) u16 xs[10 * 34 * 64];    // [row][col][ci-half] 43520 B
    __shared__ __align__(16) u16 ab[2][8192];         // A double buffer, 2x16 KB

    const int b = blockIdx.y;
    const int t = blockIdx.x;                 // 0..255
    const int swzt = (t & 7) * 32 + (t >> 3); // XCD-aware swizzle (256 % 8 == 0)
    const int tx = swzt & 7, ty = swzt >> 3;
    const int y0 = ty * 8, x0 = tx * 32;
    const int tid = threadIdx.x;
    const int lane = tid & 63, wv = tid >> 6;
    const int l31 = lane & 31;                // px-col / co-row within MFMA tile
    const int l5 = lane >> 5;                 // k-group select
    const int coHalf = (wv & 1) * 64;         // wave co origin
    const int py0w = (wv >> 1) * 2;           // wave row origin (2 rows/wave)

    const char* xbB = (const char*)g_xb;
    const char* wtbB = (const char*)(g_wtb) + (size_t)b * 294912;
    char* xsB = (char*)xs;

    f32x16 acc[2][2];
    #pragma unroll
    for (int mf = 0; mf < 2; ++mf)
        #pragma unroll
        for (int rf = 0; rf < 2; ++rf)
            acc[mf][rf] = (f32x16){0.f};

    for (int h = 0; h < 2; ++h) {
        // ---- stage X ci-half h from g_xb: 10 rows x (4 glds16 + 1 glds4) ----
        for (int i = wv; i < 50; i += 8) {
            int row = i / 5, sub = i - row * 5;
            size_t pixb = ((size_t)(b * 258 + y0 + row) * 258 + x0) * 256 + h * 128;
            char* dst = xsB + row * 4352;
            if (sub < 4) {
                // 8 px per inst: lane l -> px c = sub*8 + l/8, byte (l&7)*16 within 128B half
                glds16(xbB + pixb + (size_t)(sub * 8 + (lane >> 3)) * 256 + (lane & 7) * 16,
                       dst + sub * 1024);
            } else {
                // last 2 px: lane l -> px 32 + l/32, byte (l&31)*4
                glds4(xbB + pixb + (size_t)(32 + (lane >> 5)) * 256 + (lane & 31) * 4,
                      dst + 4096);
            }
        }
        if (h == 0) {
            // stage A step 0 (tap 0, chunk 0)
            #pragma unroll
            for (int q = 0; q < 2; ++q) {
                int j = wv * 2 + q;
                glds16(wtbB + j * 1024 + lane * 16, (char*)ab[0] + j * 1024);
            }
        }
        __syncthreads();

        for (int tap = 0; tap < 9; ++tap) {
            int s = h * 9 + tap;
            if (s < 17) {
                int ns = s + 1;
                int ntap = (ns >= 9) ? (ns - 9) : ns;
                int nh = (ns >= 9) ? 1 : h;
                const char* src = wtbB + (ntap * 2 + nh) * 16384;
                char* dst = (char*)ab[ns & 1];
                #pragma unroll
                for (int q = 0; q < 2; ++q) {
                    int j = wv * 2 + q;
                    glds16(src + j * 1024 + lane * 16, dst + j * 1024);
                }
            }

            const int ky = tap / 3, kx = tap - ky * 3;
            const char* abuf = (const char*)ab[s & 1];
            const int bcol = l31 + kx;                 // xs col 0..33
            const int bkey = bcol & 7;                 // x0 % 8 == 0
            const int brow_base = (py0w + ky) * 34 + bcol;

            #pragma unroll
            for (int ks = 0; ks < 4; ++ks) {           // K = 64 per half, steps of 16
                const int cig = ks * 2 + l5;           // 16B-slot 0..7
                bf16x8 af[2];
                #pragma unroll
                for (int mf = 0; mf < 2; ++mf) {
                    int co = coHalf + mf * 32 + l31;
                    af[mf] = *(const bf16x8*)(abuf + co * 128 + ((cig ^ (co & 7)) << 4));
                }
                bf16x8 bf[2];
                #pragma unroll
                for (int rf = 0; rf < 2; ++rf)
                    bf[rf] = *(const bf16x8*)(xsB + (brow_base + rf * 34) * 128 +
                                              ((cig ^ bkey) << 4));
                __builtin_amdgcn_s_setprio(1);
                #pragma unroll
                for (int mf = 0; mf < 2; ++mf)
                    #pragma unroll
                    for (int rf = 0; rf < 2; ++rf)
                        acc[mf][rf] = __builtin_amdgcn_mfma_f32_32x32x16_bf16(
                            af[mf], bf[rf], acc[mf][rf], 0, 0, 0);
                __builtin_amdgcn_s_setprio(0);
            }
            __syncthreads();
        }
    }

    // ---- epilogue: C layout (32x32): col = lane&31, row = (j&3)+8*(j>>2)+4*(lane>>5) ----
    float* yb = y + (size_t)b * 128 * 65536;
    #pragma unroll
    for (int mf = 0; mf < 2; ++mf) {
        #pragma unroll
        for (int rf = 0; rf < 2; ++rf) {
            int gy = y0 + py0w + rf;
            int gx = x0 + l31;
            #pragma unroll
            for (int j = 0; j < 16; ++j) {
                int co = coHalf + mf * 32 + (j & 3) + 8 * (j >> 2) + 4 * l5;
                yb[(size_t)co * 65536 + gy * 256 + gx] = acc[mf][rf][j];
            }
        }
    }
}

extern "C" void kernel_launch(void* const* d_in, const int* in_sizes, int n_in,
                              void* d_out, int out_size, void* d_ws, size_t ws_size,
                              hipStream_t stream) {
    const float* x = (const float*)d_in[0];
    const float* style = (const float*)d_in[1];
    const float* w_base = (const float*)d_in[2];
    const float* aff_w = (const float*)d_in[3];
    const float* aff_b = (const float*)d_in[4];
    float* y = (float*)d_out;

    affine_kernel<<<BB, 128, 0, stream>>>(style, aff_w, aff_b);
    modulate_kernel<<<BB * 128, 256, 0, stream>>>(w_base);
    zero_border_kernel<<<BB, 256, 0, stream>>>();
    transpose_kernel<<<dim3(4, 256, BB), 256, 0, stream>>>(x);
    conv_kernel<<<dim3(256, BB), 512, 0, stream>>>(y);
}